// Round 1
// baseline (1977.528 us; speedup 1.0000x reference)
//
#include <hip/hip_runtime.h>
#include <stdint.h>

typedef __bf16   bf16x8 __attribute__((ext_vector_type(8)));
typedef float    f32x4  __attribute__((ext_vector_type(4)));
typedef uint32_t u32x4  __attribute__((ext_vector_type(4)));

#define L_SEQ 8192
#define DIM   768
#define KROW  8256   // padded row length of kR (elements)
#define KOFF  8223   // kR[d][i] = k_scaled[KOFF - i]; zeros elsewhere

// Workspace layout (bytes):
//   kR  bf16 [768][8256]     @ 0           size 12,681,216
//   uT  bf16 [768][8][8192]  @ 12,681,216  size 100,663,296
//   yT  bf16 [768][8][8192]  @ 113,344,512 size 100,663,296
// total 214,007,808 B

// ---------------- filter MLP -> kR (reversed, scaled by 1/16384) ----------
__global__ __launch_bounds__(256) void filter_kernel(
    const float* __restrict__ w_in, const float* __restrict__ b_in,
    const float* __restrict__ freq_in,
    const float* __restrict__ w_h0, const float* __restrict__ b_h0,
    const float* __restrict__ freq_h0,
    const float* __restrict__ w_h1, const float* __restrict__ b_h1,
    const float* __restrict__ freq_h1,
    const float* __restrict__ w_out,
    unsigned short* __restrict__ kR)
{
  int s = blockIdx.x;
  int tid = threadIdx.x;
  if (s == L_SEQ) {
    // zero-pad block: i in [0,32) (s>8191 side) and [8224,8256) (s<0 side)
    for (int idx = tid; idx < DIM * 64; idx += 256) {
      int d = idx >> 6, j = idx & 63;
      int i = (j < 32) ? j : (8192 + j);
      kR[d * KROW + i] = 0;
    }
    return;
  }
  __shared__ float h[64];
  __shared__ float h2[64];
  float t = s * (1.0f / 8191.0f);
  if (tid < 64) {
    float ph = s * (float)(6.283185307179586 * 1e-4 / 8192.0);
    float z1 = cosf(ph), z2 = -sinf(ph);
    float a = t * w_in[tid] + z1 * w_in[64 + tid] + z2 * w_in[128 + tid] + b_in[tid];
    h[tid] = sinf(freq_in[tid] * a);
  }
  __syncthreads();
  if (tid < 64) {
    float a = b_h0[tid];
    for (int r = 0; r < 64; ++r) a += h[r] * w_h0[r * 64 + tid];
    h2[tid] = sinf(freq_h0[tid] * a);
  }
  __syncthreads();
  if (tid < 64) {
    float a = b_h1[tid];
    for (int r = 0; r < 64; ++r) a += h2[r] * w_h1[r * 64 + tid];
    h[tid] = sinf(freq_h1[tid] * a);  // h <- h3
  }
  __syncthreads();
  for (int d = tid; d < DIM; d += 256) {
    float a = 0.0f;
    for (int r = 0; r < 64; ++r) a += h[r] * w_out[r * DIM + d];
    float delta = fabsf(-3.070113457f - 12.280453827f * (d * (1.0f / 767.0f)));
    float decay = expf(-t * delta);
    float val = a * decay * 6.103515625e-05f;  // fold 1/fft_size
    kR[d * KROW + (KOFF - s)] = __builtin_bit_cast(unsigned short, (__bf16)val);
  }
}

// ---------------- x (B,L,D) fp32 -> uT[d][b][t] bf16 ----------------------
__global__ __launch_bounds__(256) void transpose_in_kernel(
    const float* __restrict__ x, unsigned short* __restrict__ uT)
{
  __shared__ unsigned short tile[64][66];
  int b = blockIdx.z;
  int t0 = blockIdx.y * 64;
  int d0 = blockIdx.x * 64;
  int tid = threadIdx.x;
  int j = tid & 63, i0 = tid >> 6;
  for (int ii = 0; ii < 16; ++ii) {
    int tt = i0 * 16 + ii;
    float v = x[((size_t)b * L_SEQ + t0 + tt) * DIM + d0 + j];
    tile[tt][j] = __builtin_bit_cast(unsigned short, (__bf16)v);
  }
  __syncthreads();
  for (int ii = 0; ii < 16; ++ii) {
    int dd = i0 + ii * 4;
    uT[((size_t)(d0 + dd) * 8 + b) * L_SEQ + t0 + j] = tile[j][dd];
  }
}

// ---------------- conv: yT[d][b][t] = sum_tau u[b][tau] k[t-tau] ----------
__global__ __launch_bounds__(256) void conv_kernel(
    const unsigned short* __restrict__ kR,
    const unsigned short* __restrict__ uT,
    unsigned short* __restrict__ yT)
{
  const int d   = blockIdx.y;
  const int T0  = blockIdx.x << 8;       // t-span 256
  const int tid = threadIdx.x;
  const int lane = tid & 63;
  const int w    = tid >> 6;
  __shared__ uint32_t dupK[288];         // dup window: dword i = (kR[i0+i], kR[i0+i+1])
  __shared__ uint32_t uwinW[8][20];      // u window: [b][tau 32 bf16 in 16 dw], stride 20 dw
  f32x4 acc[4] = {};

  // per-channel truncation: skip tau where decay < 0.03 (err ~2e-4 << 6.8e-2)
  float delta = fabsf(-3.070113457f - 12.280453827f * (d * (1.0f / 767.0f)));
  int S = (int)(8191.0f * 3.5065578f / delta);
  int tau_start = T0 - S;
  tau_start = (tau_start < 0) ? 0 : (tau_start & ~31);

  const unsigned short* kRd = kR + d * KROW;
  const uint32_t* uTd = (const uint32_t*)uT + (size_t)d * 8 * 4096;
  const int m = lane & 15, q = lane >> 4;

  for (int tau0 = tau_start; tau0 <= T0 + 224; tau0 += 32) {
    if (tid < 128) {
      int bb = tid >> 4, r = tid & 15;
      uwinW[bb][r] = uTd[bb * 4096 + (tau0 >> 1) + r];
    }
    int i0 = 7968 - T0 + tau0;
    for (int ww = tid; ww < 288; ww += 256) {
      unsigned ia = (unsigned)(i0 + ww);
      unsigned ib2 = ia + 1u;
      if (ia  > 8255u) ia  = 8255u;   // out-of-range -> kR[8255] == 0
      if (ib2 > 8255u) ib2 = 8255u;
      dupK[ww] = (uint32_t)kRd[ia] | ((uint32_t)kRd[ib2] << 16);
    }
    __syncthreads();

    // A fragment: A[m][8q+j] = u[m&7][tau0+8q+j]  (rows 8..15 duplicate 0..7)
    bf16x8 afrag = *(const bf16x8*)&uwinW[m & 7][q * 4];

#pragma unroll
    for (int st = 0; st < 4; ++st) {
      // B fragment: B[8q+j][n=m] = k[t0+n-tau0-8q-j] = kR[i0+ib+j]
      int ib = 255 - ((w * 4 + st) << 4) - m + (q << 3);
      u32x4 bu = { dupK[ib], dupK[ib + 2], dupK[ib + 4], dupK[ib + 6] };
      bf16x8 bfrag = __builtin_bit_cast(bf16x8, bu);
      acc[st] = __builtin_amdgcn_mfma_f32_16x16x32_bf16(afrag, bfrag, acc[st], 0, 0, 0);
    }
    __syncthreads();
  }

  // C[row][col]: col = lane&15 = t-offset, row = (lane>>4)*4 + reg = batch
  if (q < 2) {
#pragma unroll
    for (int st = 0; st < 4; ++st) {
      int t0 = T0 + ((w * 4 + st) << 4);
#pragma unroll
      for (int r = 0; r < 4; ++r) {
        int bb = q * 4 + r;
        float v = acc[st][r];
        yT[((size_t)(d * 8 + bb) << 13) + t0 + m] =
            __builtin_bit_cast(unsigned short, (__bf16)v);
      }
    }
  }
}

// ---------------- yT[d][b][t] bf16 -> out (B,L,D) fp32 + bias -------------
__global__ __launch_bounds__(256) void transpose_out_kernel(
    const unsigned short* __restrict__ yT, const float* __restrict__ bias,
    float* __restrict__ out)
{
  __shared__ float tile[64][65];
  int b = blockIdx.z;
  int t0 = blockIdx.y * 64;
  int d0 = blockIdx.x * 64;
  int tid = threadIdx.x;
  int j = tid & 63, i0 = tid >> 6;
  for (int ii = 0; ii < 16; ++ii) {
    int dd = i0 * 16 + ii;
    unsigned short v = yT[((size_t)(d0 + dd) * 8 + b) * L_SEQ + t0 + j];
    tile[dd][j] = (float)__builtin_bit_cast(__bf16, v);
  }
  __syncthreads();
  float bs = bias[d0 + j];
  for (int ii = 0; ii < 16; ++ii) {
    int tt = i0 + ii * 4;
    out[((size_t)b * L_SEQ + t0 + tt) * DIM + d0 + j] = tile[j][tt] + bs;
  }
}

extern "C" void kernel_launch(void* const* d_in, const int* in_sizes, int n_in,
                              void* d_out, int out_size, void* d_ws, size_t ws_size,
                              hipStream_t stream)
{
  const float* x       = (const float*)d_in[0];
  const float* w_in    = (const float*)d_in[1];
  const float* b_in    = (const float*)d_in[2];
  const float* freq_in = (const float*)d_in[3];
  const float* w_h0    = (const float*)d_in[4];
  const float* b_h0    = (const float*)d_in[5];
  const float* freq_h0 = (const float*)d_in[6];
  const float* w_h1    = (const float*)d_in[7];
  const float* b_h1    = (const float*)d_in[8];
  const float* freq_h1 = (const float*)d_in[9];
  const float* w_out   = (const float*)d_in[10];
  const float* bias    = (const float*)d_in[11];

  char* ws = (char*)d_ws;
  unsigned short* kR = (unsigned short*)(ws);
  unsigned short* uT = (unsigned short*)(ws + 12681216);
  unsigned short* yT = (unsigned short*)(ws + 113344512);
  float* out = (float*)d_out;

  hipLaunchKernelGGL(filter_kernel, dim3(L_SEQ + 1), dim3(256), 0, stream,
                     w_in, b_in, freq_in, w_h0, b_h0, freq_h0,
                     w_h1, b_h1, freq_h1, w_out, kR);
  hipLaunchKernelGGL(transpose_in_kernel, dim3(12, 128, 8), dim3(256), 0, stream, x, uT);
  hipLaunchKernelGGL(conv_kernel, dim3(32, 768), dim3(256), 0, stream, kR, uT, yT);
  hipLaunchKernelGGL(transpose_out_kernel, dim3(12, 128, 8), dim3(256), 0, stream,
                     yT, bias, out);
}

// Round 2
// 1489.749 us; speedup vs baseline: 1.3274x; 1.3274x over previous
//
#include <hip/hip_runtime.h>
#include <stdint.h>

typedef __bf16   bf16x8 __attribute__((ext_vector_type(8)));
typedef float    f32x4  __attribute__((ext_vector_type(4)));
typedef uint32_t u32x4  __attribute__((ext_vector_type(4)));

#define L_SEQ 8192
#define DIM   768
#define DROW  8768     // dupG row length in dwords (zero-padded tail)
// dupG[d][i] = ( k[8223-i], k[8222-i] ) as packed bf16 pair, scaled by 1/16384.
// k[s]=0 for s<0 or s>8191  ->  dupG zero for i<31 and i>=8224.

// Workspace layout (bytes):
//   dupG u32  [768][8768]    @ 0            size 26,935,296
//   uT   bf16 [768][8][8192] @ 26,935,296   size 100,663,296
//   yT   bf16 [768][8][8192] @ 127,598,592  size 100,663,296
// total 228,261,888 B

// ---------------- zero the dupG pad regions (re-poisoned every call) ------
__global__ __launch_bounds__(256) void pad_kernel(uint32_t* __restrict__ dupG)
{
  int d = blockIdx.x;
  const int NPAD = 31 + (DROW - 8224);
  for (int j = threadIdx.x; j < NPAD; j += 256) {
    int i = (j < 31) ? j : 8224 + (j - 31);
    dupG[(size_t)d * DROW + i] = 0u;
  }
}

// ---------------- filter MLP -> dupG pairs --------------------------------
// block c covers s in [32c, 32c+31]; computes K[j] = k[32c-1+j], j in [0,33)
__global__ __launch_bounds__(256) void filter_kernel(
    const float* __restrict__ w_in, const float* __restrict__ b_in,
    const float* __restrict__ freq_in,
    const float* __restrict__ w_h0, const float* __restrict__ b_h0,
    const float* __restrict__ freq_h0,
    const float* __restrict__ w_h1, const float* __restrict__ b_h1,
    const float* __restrict__ freq_h1,
    const float* __restrict__ w_out,
    uint32_t* __restrict__ dupG)
{
  __shared__ float h1[33][65];
  __shared__ float h2[33][65];
  __shared__ unsigned short kv[33][64];
  __shared__ float wch[64][64];           // w_out chunk [r][dd]

  const int c = blockIdx.x;               // 0..255
  const int sbase = c << 5;
  const int tid = threadIdx.x;

  // layer 1 (EMB=3 features)
  for (int p = tid; p < 33 * 64; p += 256) {
    int j = p >> 6, n = p & 63;
    int s = sbase - 1 + j;
    float t  = s * (1.0f / 8191.0f);
    float ph = s * (float)(6.283185307179586 * 1e-4 / 8192.0);
    float a = t * w_in[n] + cosf(ph) * w_in[64 + n] + (-sinf(ph)) * w_in[128 + n] + b_in[n];
    h1[j][n] = sinf(freq_in[n] * a);
  }
  __syncthreads();
  for (int p = tid; p < 33 * 64; p += 256) {
    int j = p >> 6, n = p & 63;
    float a = b_h0[n];
    for (int r = 0; r < 64; ++r) a += h1[j][r] * w_h0[r * 64 + n];
    h2[j][n] = sinf(freq_h0[n] * a);
  }
  __syncthreads();
  for (int p = tid; p < 33 * 64; p += 256) {
    int j = p >> 6, n = p & 63;
    float a = b_h1[n];
    for (int r = 0; r < 64; ++r) a += h2[j][r] * w_h1[r * 64 + n];
    h1[j][n] = sinf(freq_h1[n] * a);      // h1 <- h3
  }
  __syncthreads();

  for (int dc = 0; dc < 12; ++dc) {
    for (int p = tid; p < 64 * 64; p += 256) {
      int r = p >> 6, dd = p & 63;
      wch[r][dd] = w_out[r * DIM + dc * 64 + dd];
    }
    __syncthreads();
    for (int p = tid; p < 33 * 64; p += 256) {
      int j = p >> 6, dd = p & 63;
      float a = 0.0f;
      for (int r = 0; r < 64; ++r) a += h1[j][r] * wch[r][dd];
      int s = sbase - 1 + j;
      int d = dc * 64 + dd;
      float delta = fabsf(-3.070113457f - 12.280453827f * (d * (1.0f / 767.0f)));
      float t = s * (1.0f / 8191.0f);
      float val = (s < 0) ? 0.0f : a * expf(-t * delta) * 6.103515625e-05f;
      kv[j][dd] = __builtin_bit_cast(unsigned short, (__bf16)val);
    }
    __syncthreads();
    // dup[8223-s] = (k[s], k[s-1]) for s = sbase+j, j in [0,32)
    for (int p = tid; p < 32 * 64; p += 256) {
      int j = p >> 6, dd = p & 63;
      int d = dc * 64 + dd;
      int i = 8223 - (sbase + j);
      dupG[(size_t)d * DROW + i] =
          (uint32_t)kv[j + 1][dd] | ((uint32_t)kv[j][dd] << 16);
    }
    if (c == 255 && tid < 64) {
      int d = dc * 64 + tid;
      dupG[(size_t)d * DROW + 31] = ((uint32_t)kv[32][tid] << 16); // (0, k[8191])
    }
    __syncthreads();
  }
}

// ---------------- x (B,L,D) fp32 -> uT[d][b][t] bf16 ----------------------
__global__ __launch_bounds__(256) void transpose_in_kernel(
    const float* __restrict__ x, unsigned short* __restrict__ uT)
{
  __shared__ unsigned short tile[64][66];
  int b = blockIdx.z;
  int t0 = blockIdx.y * 64;
  int d0 = blockIdx.x * 64;
  int tid = threadIdx.x;
  int j = tid & 63, i0 = tid >> 6;
  for (int ii = 0; ii < 16; ++ii) {
    int tt = i0 * 16 + ii;
    float v = x[((size_t)b * L_SEQ + t0 + tt) * DIM + d0 + j];
    tile[tt][j] = __builtin_bit_cast(unsigned short, (__bf16)v);
  }
  __syncthreads();
  for (int ii = 0; ii < 16; ++ii) {
    int dd = i0 + ii * 4;
    uT[((size_t)(d0 + dd) * 8 + b) * L_SEQ + t0 + j] = tile[j][dd];
  }
}

// ---------------- conv: yT[d][b][t] = sum_tau u[b][tau] k[t-tau] ----------
// t-span 512/block; 8 MFMA sub-tiles per wave; rolling B-fragments.
#define LOADFRAG(dst, absdw) {                                   \
    int _p = ((absdw) & 1023);                                   \
    u32x4 _u = { buf[_p], buf[_p + 2], buf[_p + 4], buf[_p + 6] };\
    dst = __builtin_bit_cast(bf16x8, _u); }

__global__ __launch_bounds__(256) void conv_kernel(
    const uint32_t* __restrict__ dupG,
    const unsigned short* __restrict__ uT,
    unsigned short* __restrict__ yT)
{
  const int d   = blockIdx.y;
  const int T0  = blockIdx.x << 9;       // t-span 512
  const int tid = threadIdx.x;
  const int lane = tid & 63;
  const int w    = tid >> 6;
  const int m = lane & 15, q = lane >> 4;
  __shared__ uint32_t buf[1056];         // 1024 circular + 32 mirror

  f32x4 acc[8] = {};
  bf16x8 fr[8];

  float delta = fabsf(-3.070113457f - 12.280453827f * (d * (1.0f / 767.0f)));
  int S = (int)(8191.0f * 3.5065578f / delta);   // decay < 0.03 cutoff
  int tau_start = T0 - S;
  tau_start = (tau_start < 0) ? 0 : (tau_start & ~31);
  int niter = ((T0 + 480 - tau_start) >> 5) + 1;
  niter = (niter + 3) & ~3;              // pad with zero-contribution iters

  const uint32_t* dG = dupG + (size_t)d * DROW;
  const unsigned short* uTd = uT + ((size_t)d << 16);

  int i0 = 7712 - T0 + tau_start;        // window base (dword idx), >= 32

  // prefill window [i0, i0+520)
  for (int j = tid; j < 520; j += 256) {
    int i = i0 + j;
    uint32_t v = dG[i];
    int pos = i & 1023;
    buf[pos] = v;
    if (pos < 32) buf[1024 + pos] = v;
  }
  __syncthreads();

  // per-lane bases
  int a_off = ((lane & 7) << 14) + ((tau_start + (q << 3)) << 1);  // bytes into uTd
  int vb = i0 + 511 - (w << 7) - m + (q << 3);                     // abs dword, st=0
  int chunk_i = i0 + 520;

  // prologue: fragments for st=2..7 of iteration 0
  LOADFRAG(fr[6], vb - 32);
  LOADFRAG(fr[7], vb - 48);
  LOADFRAG(fr[4], vb - 64);
  LOADFRAG(fr[5], vb - 80);
  LOADFRAG(fr[2], vb - 96);
  LOADFRAG(fr[3], vb - 112);

#define MFMA_ST(rr, st)                                                        \
  acc[st] = __builtin_amdgcn_mfma_f32_16x16x32_bf16(                           \
      afrag, fr[(2 * (rr) - 2 * ((st) >> 1) + ((st) & 1)) & 7], acc[st], 0, 0, 0);

#define BODY(rr) {                                                             \
    bf16x8 afrag = *(const bf16x8*)((const char*)uTd + a_off + ((rr) << 6));   \
    if (tid < 32) {                                                            \
      int i = chunk_i + ((rr) << 5) + tid;                                     \
      int iv = (i < 8744) ? i : 8744;   /* clamp into zero tail */             \
      uint32_t v = dG[iv];                                                     \
      int pos = i & 1023;                                                      \
      buf[pos] = v;                                                            \
      if (pos < 32) buf[1024 + pos] = v;                                       \
    }                                                                          \
    __syncthreads();                                                           \
    int vbr = vb + ((rr) << 5);                                                \
    LOADFRAG(fr[(2 * (rr)) & 7], vbr);                                         \
    LOADFRAG(fr[(2 * (rr) + 1) & 7], vbr - 16);                                \
    MFMA_ST(rr, 2) MFMA_ST(rr, 3) MFMA_ST(rr, 4) MFMA_ST(rr, 5)                \
    MFMA_ST(rr, 6) MFMA_ST(rr, 7) MFMA_ST(rr, 0) MFMA_ST(rr, 1)                \
  }

  for (int nn = 0; nn < niter; nn += 4) {
    BODY(0) BODY(1) BODY(2) BODY(3)
    a_off   += 256;   // 128 elements
    vb      += 128;   // dwords
    chunk_i += 128;
  }

  // C[row][col]: col = lane&15 = t-offset, row = (lane>>4)*4 + reg = batch
  if (q < 2) {
#pragma unroll
    for (int st = 0; st < 8; ++st) {
      int t0 = T0 + ((w * 8 + st) << 4);
#pragma unroll
      for (int r = 0; r < 4; ++r) {
        int bb = q * 4 + r;
        yT[((size_t)(d * 8 + bb) << 13) + t0 + m] =
            __builtin_bit_cast(unsigned short, (__bf16)acc[st][r]);
      }
    }
  }
}

// ---------------- yT[d][b][t] bf16 -> out (B,L,D) fp32 + bias -------------
__global__ __launch_bounds__(256) void transpose_out_kernel(
    const unsigned short* __restrict__ yT, const float* __restrict__ bias,
    float* __restrict__ out)
{
  __shared__ float tile[64][65];
  int b = blockIdx.z;
  int t0 = blockIdx.y * 64;
  int d0 = blockIdx.x * 64;
  int tid = threadIdx.x;
  int j = tid & 63, i0 = tid >> 6;
  for (int ii = 0; ii < 16; ++ii) {
    int dd = i0 * 16 + ii;
    unsigned short v = yT[((size_t)(d0 + dd) * 8 + b) * L_SEQ + t0 + j];
    tile[dd][j] = (float)__builtin_bit_cast(__bf16, v);
  }
  __syncthreads();
  float bs = bias[d0 + j];
  for (int ii = 0; ii < 16; ++ii) {
    int tt = i0 + ii * 4;
    out[((size_t)b * L_SEQ + t0 + tt) * DIM + d0 + j] = tile[j][tt] + bs;
  }
}

extern "C" void kernel_launch(void* const* d_in, const int* in_sizes, int n_in,
                              void* d_out, int out_size, void* d_ws, size_t ws_size,
                              hipStream_t stream)
{
  const float* x       = (const float*)d_in[0];
  const float* w_in    = (const float*)d_in[1];
  const float* b_in    = (const float*)d_in[2];
  const float* freq_in = (const float*)d_in[3];
  const float* w_h0    = (const float*)d_in[4];
  const float* b_h0    = (const float*)d_in[5];
  const float* freq_h0 = (const float*)d_in[6];
  const float* w_h1    = (const float*)d_in[7];
  const float* b_h1    = (const float*)d_in[8];
  const float* freq_h1 = (const float*)d_in[9];
  const float* w_out   = (const float*)d_in[10];
  const float* bias    = (const float*)d_in[11];

  char* ws = (char*)d_ws;
  uint32_t* dupG = (uint32_t*)(ws);
  unsigned short* uT = (unsigned short*)(ws + 26935296);
  unsigned short* yT = (unsigned short*)(ws + 127598592);
  float* out = (float*)d_out;

  hipLaunchKernelGGL(pad_kernel, dim3(DIM), dim3(256), 0, stream, dupG);
  hipLaunchKernelGGL(filter_kernel, dim3(256), dim3(256), 0, stream,
                     w_in, b_in, freq_in, w_h0, b_h0, freq_h0,
                     w_h1, b_h1, freq_h1, w_out, dupG);
  hipLaunchKernelGGL(transpose_in_kernel, dim3(12, 128, 8), dim3(256), 0, stream, x, uT);
  hipLaunchKernelGGL(conv_kernel, dim3(16, DIM), dim3(256), 0, stream, dupG, uT, yT);
  hipLaunchKernelGGL(transpose_out_kernel, dim3(12, 128, 8), dim3(256), 0, stream,
                     yT, bias, out);
}